// Round 1
// 414.576 us; speedup vs baseline: 1.0258x; 1.0258x over previous
//
#include <hip/hip_runtime.h>

#define H 1024
#define W 1024
#define HW (H * W)
#define STRIP 32
#define LDSROW 1032   // 2 halo + 1024 cols + 2 halo + pad (row start stays 16B-aligned)
#define NSLOT 6       // 6-slot row ring -> 24768 B LDS -> 6 blocks/CU

// Bit-exact emulation of the numpy fp32 reference (verified earlier, absmax pass):
// direct 9-tap correlation, row-major tap order, sequential fp32 adds.
// fmaf by +-2/+-4 is bit-identical to mul+add (power-of-2 products exact).
// det = p1 - p2 must NOT be contracted -> contract(off).
__device__ __forceinline__ float score_ref(
    float a00, float a01, float a02,
    float a10, float a11, float a12,
    float a20, float a21, float a22)
{
#pragma clang fp contract(off)
    float gxx = fmaf(-2.0f, a01, a00);
    gxx = gxx + a02;
    gxx = fmaf(2.0f, a10, gxx);
    gxx = fmaf(-4.0f, a11, gxx);
    gxx = fmaf(2.0f, a12, gxx);
    gxx = gxx + a20;
    gxx = fmaf(-2.0f, a21, gxx);
    gxx = gxx + a22;
    float gxy = a02 - a00;
    gxy = gxy + a20;
    gxy = gxy - a22;
    float gyy = fmaf(2.0f, a01, a00);
    gyy = gyy + a02;
    gyy = fmaf(-2.0f, a10, gyy);
    gyy = fmaf(-4.0f, a11, gyy);
    gyy = fmaf(-2.0f, a12, gyy);
    gyy = gyy + a20;
    gyy = fmaf(2.0f, a21, gyy);
    gyy = gyy + a22;

    float p1 = gxx * gyy;
    float p2 = gxy * gxy;
    float det = p1 - p2;
    float s = fabsf(det);
    return s > 1e-6f ? s : 1e-6f;
}

struct Row8 { float a[8]; };   // input cols c-2 .. c+5 (c = 4*t)

// Clamped, fully-coalesced row load: exactly one float4 (16 B) per lane.
__device__ __forceinline__ float4 load_row4(const float* __restrict__ px, int row, int t)
{
    row = row < 0 ? 0 : (row > H - 1 ? H - 1 : row);
    return *(const float4*)(px + (size_t)row * W + (t << 2));
}

// LDS row layout: lds[j] = x[row][clamp(j-2, 0, 1023)], j in [0,1028).
// Main payload written as two 8B-aligned float2 (ds_write_b64); halo by t==0/t==255.
__device__ __forceinline__ void stage_row(float* lds, int slot, float4 v, int t)
{
    float* p = lds + slot * LDSROW;
    float* q = p + 2 + (t << 2);
    *(float2*)(q)     = make_float2(v.x, v.y);
    *(float2*)(q + 2) = make_float2(v.z, v.w);
    if (t == 0)   { p[0] = v.x; p[1] = v.x; }          // cols -2,-1 -> x[0]
    if (t == 255) { p[1026] = v.w; p[1027] = v.w; }    // cols 1024,1025 -> x[1023]
}

// Window cols c-2..c+5 = lds[4t .. 4t+7]: two 16B-aligned ds_read_b128.
__device__ __forceinline__ Row8 read_win(const float* lds, int slot, int t)
{
    const float* p = lds + slot * LDSROW + (t << 2);
    float4 lo = *(const float4*)(p);
    float4 hi = *(const float4*)(p + 4);
    Row8 r;
    r.a[0] = lo.x; r.a[1] = lo.y; r.a[2] = lo.z; r.a[3] = lo.w;
    r.a[4] = hi.x; r.a[5] = hi.y; r.a[6] = hi.z; r.a[7] = hi.w;
    return r;
}

// ---------------- K1: per-plane max (order-free math -> separable) ----------
__global__ __launch_bounds__(256) void hess_max_kernel(
    const float* __restrict__ x, unsigned int* __restrict__ pmax)
{
    __shared__ float lds[NSLOT * LDSROW];
    const int plane = blockIdx.y;
    const int y0 = blockIdx.x * STRIP;
    const int t = threadIdx.x;
    const float* px = x + (size_t)plane * HW;

    // Prologue: rows y0-1, y0 staged; gv = row y0+1 in flight.
    stage_row(lds, 0, load_row4(px, y0 - 1, t), t);
    stage_row(lds, 1, load_row4(px, y0, t), t);
    float4 gv = load_row4(px, y0 + 1, t);
    __syncthreads();
    Row8 A = read_win(lds, 0, t);   // row sy-1
    Row8 B = read_win(lds, 1, t);   // row sy

    float smax = 1e-6f;
    int sw = 2;
    for (int i = 0; i < STRIP; ++i) {
        const int sy = y0 + i;
        // invariant: gv holds row sy+1 (issued after the PREVIOUS barrier,
        // so the vmcnt drain at this barrier doesn't serialize the prefetch)
        stage_row(lds, sw, gv, t);
        __syncthreads();
        gv = load_row4(px, sy + 2, t);          // prefetch next ring row

        Row8 C = read_win(lds, sw, t);          // row sy+1
        sw = (sw + 1 == NSLOT) ? 0 : sw + 1;

        float P[6], Q[6], Rv[6];
#pragma unroll
        for (int k = 0; k < 6; ++k) {
            // vertical partials at col c-1+k (window index k+1)
            P[k]  = fmaf(2.0f, B.a[k + 1], A.a[k + 1]) + C.a[k + 1];
            Q[k]  = fmaf(-2.0f, B.a[k + 1], A.a[k + 1]) + C.a[k + 1];
            Rv[k] = A.a[k + 1] - C.a[k + 1];
        }
#pragma unroll
        for (int j = 0; j < 4; ++j) {
            float gxx = fmaf(-2.0f, P[j + 1], P[j]) + P[j + 2];
            float gyy = fmaf(2.0f, Q[j + 1], Q[j]) + Q[j + 2];
            float gxy = Rv[j + 2] - Rv[j];
            float det = fmaf(gxx, gyy, -(gxy * gxy));
            smax = fmaxf(smax, fabsf(det));
        }
        A = B; B = C;
    }

#pragma unroll
    for (int off = 32; off > 0; off >>= 1)
        smax = fmaxf(smax, __shfl_down(smax, off));
    if ((t & 63) == 0)
        atomicMax(pmax + plane, __float_as_uint(smax));
}

// ---------------- K2: bit-exact scores + NMS + normalize --------------------
struct S6 { float s[6]; };   // scores at cols c-1 .. c+4

__device__ __forceinline__ S6 score_row_exact(const Row8& A, const Row8& B, const Row8& C)
{
    S6 o;
#pragma unroll
    for (int i = 0; i < 6; ++i)
        o.s[i] = score_ref(A.a[i], A.a[i + 1], A.a[i + 2],
                           B.a[i], B.a[i + 1], B.a[i + 2],
                           C.a[i], C.a[i + 1], C.a[i + 2]);
    return o;
}

__global__ __launch_bounds__(256) void hess_nms_kernel(
    const float* __restrict__ x, const unsigned int* __restrict__ pmax,
    float* __restrict__ out)
{
    __shared__ float lds[NSLOT * LDSROW];
    const int plane = blockIdx.y;
    const int y0 = blockIdx.x * STRIP;
    const int t = threadIdx.x;
    const float* px = x + (size_t)plane * HW;
    float* po = out + (size_t)plane * HW;
    const float inv = 1.0f / __uint_as_float(pmax[plane]);

    // Prologue: rows y0-2 .. y0+2 staged into slots 0..4; gv = row y0+3 in flight.
    stage_row(lds, 0, load_row4(px, y0 - 2, t), t);
    stage_row(lds, 1, load_row4(px, y0 - 1, t), t);
    stage_row(lds, 2, load_row4(px, y0,     t), t);
    stage_row(lds, 3, load_row4(px, y0 + 1, t), t);
    stage_row(lds, 4, load_row4(px, y0 + 2, t), t);
    float4 gv = load_row4(px, y0 + 3, t);
    __syncthreads();
    Row8 rm2 = read_win(lds, 0, t);
    Row8 r0  = read_win(lds, 1, t);
    Row8 r1  = read_win(lds, 2, t);   // row sy
    Row8 r2  = read_win(lds, 3, t);   // row sy+1
    Row8 r3  = read_win(lds, 4, t);   // row sy+2

    S6 zero;
#pragma unroll
    for (int i = 0; i < 6; ++i) zero.s[i] = 0.0f;

    // score row y0-1 (OOB -> zeros, the identity for the 3x3 max)
    S6 sp = zero;
    if (y0 > 0) sp = score_row_exact(rm2, r0, r1);
    S6 sc_ = score_row_exact(r0, r1, r2);

    int sw = 5;
    for (int i = 0; i < STRIP; ++i) {
        const int sy = y0 + i;
        // invariant: gv holds row sy+3 (issued after the previous barrier)
        stage_row(lds, sw, gv, t);
        __syncthreads();
        gv = load_row4(px, sy + 4, t);          // prefetch next ring row

        S6 sn = zero;
        if (sy + 1 < H) sn = score_row_exact(r1, r2, r3);

        float4 o;
        float* ov = (float*)&o;
#pragma unroll
        for (int j = 0; j < 4; ++j) {
            float s = sc_.s[j + 1];
            float m = fmaxf(fmaxf(fmaxf(sp.s[j], sp.s[j + 1]), fmaxf(sp.s[j + 2], sc_.s[j])),
                            fmaxf(fmaxf(sc_.s[j + 1], sc_.s[j + 2]),
                                  fmaxf(fmaxf(sn.s[j], sn.s[j + 1]), sn.s[j + 2])));
            ov[j] = (s == m) ? s * inv : 0.0f;
        }
        *(float4*)(po + (size_t)sy * W + (t << 2)) = o;

        Row8 r4 = read_win(lds, sw, t);         // row sy+3
        sw = (sw + 1 == NSLOT) ? 0 : sw + 1;
        r1 = r2; r2 = r3; r3 = r4;
        sp = sc_; sc_ = sn;
    }
}

extern "C" void kernel_launch(void* const* d_in, const int* in_sizes, int n_in,
                              void* d_out, int out_size, void* d_ws, size_t ws_size,
                              hipStream_t stream) {
    const float* x = (const float*)d_in[0];
    float* out = (float*)d_out;
    unsigned int* pmax = (unsigned int*)d_ws;
    const int planes = in_sizes[0] / HW;   // 48

    hipMemsetAsync(pmax, 0, planes * sizeof(unsigned int), stream);

    dim3 grid(H / STRIP, planes);
    hess_max_kernel<<<grid, 256, 0, stream>>>(x, pmax);
    hess_nms_kernel<<<grid, 256, 0, stream>>>(x, pmax, out);
}

// Round 3
// 411.677 us; speedup vs baseline: 1.0330x; 1.0070x over previous
//
#include <hip/hip_runtime.h>

#define H 1024
#define W 1024
#define HW (H * W)
#define STRIP 32
#define SLOTF 1024            // floats per LDS row slot (no halo; clamp on read)
#define RING 6                // 6-slot ring -> 24576 B LDS, 6 blocks/CU cap

typedef __attribute__((address_space(3))) float lds_f;
typedef const __attribute__((address_space(1))) float g_f;
typedef float nfloat4 __attribute__((ext_vector_type(4)));   // native vec for NT store

// Direct global->LDS DMA, 16B per lane. Dest = wave-uniform base + lane*16
// (our layout: wave w owns floats [256w, 256w+256) of the slot). Src per-lane.
__device__ __forceinline__ void gload16(const float* g, float* l) {
    __builtin_amdgcn_global_load_lds((g_f*)g, (lds_f*)l, 16, 0, 0);
}

// Counted wait + raw barrier in ONE asm with memory clobber: no memory op
// (ds_read, global store, DMA issue) can be moved across it by the compiler,
// which is what makes the FIFO vmcnt accounting below sound.
template<int N>
__device__ __forceinline__ void wait_vm_barrier() {
    asm volatile("s_waitcnt vmcnt(%0)\n\ts_barrier" :: "i"(N) : "memory");
}
__device__ __forceinline__ void barrier_only() {
    asm volatile("s_barrier" ::: "memory");
}

// Issue one row-DMA into a slot (row clamped for edge replication).
__device__ __forceinline__ void stage(const float* px, int row, float* slotbase, int wq, int t) {
    row = row < 0 ? 0 : (row > H - 1 ? H - 1 : row);
    gload16(px + (size_t)row * W + (t << 2), slotbase + wq);
}

// Bit-exact emulation of the numpy fp32 reference (verified, absmax pass):
// direct 9-tap correlation, row-major tap order, sequential fp32 adds.
// fmaf by +-2/+-4 is bit-identical to mul+add (power-of-2 products exact).
// det = p1 - p2 must NOT be contracted -> contract(off).
__device__ __forceinline__ float score_ref(
    float a00, float a01, float a02,
    float a10, float a11, float a12,
    float a20, float a21, float a22)
{
#pragma clang fp contract(off)
    float gxx = fmaf(-2.0f, a01, a00);
    gxx = gxx + a02;
    gxx = fmaf(2.0f, a10, gxx);
    gxx = fmaf(-4.0f, a11, gxx);
    gxx = fmaf(2.0f, a12, gxx);
    gxx = gxx + a20;
    gxx = fmaf(-2.0f, a21, gxx);
    gxx = gxx + a22;
    float gxy = a02 - a00;
    gxy = gxy + a20;
    gxy = gxy - a22;
    float gyy = fmaf(2.0f, a01, a00);
    gyy = gyy + a02;
    gyy = fmaf(-2.0f, a10, gyy);
    gyy = fmaf(-4.0f, a11, gyy);
    gyy = fmaf(-2.0f, a12, gyy);
    gyy = gyy + a20;
    gyy = fmaf(2.0f, a21, gyy);
    gyy = gyy + a22;

    float p1 = gxx * gyy;
    float p2 = gxy * gxy;
    float det = p1 - p2;
    float s = fabsf(det);
    return s > 1e-6f ? s : 1e-6f;
}

struct Row8 { float a[8]; };   // input cols c-2 .. c+5 (c = 4*t)

// Window from an LDS slot with horizontal edge clamp (only lanes 0 / 255).
// b64 @ c-2 (8B aligned), b128 @ c (16B aligned), b64 @ c+4 (8B aligned).
__device__ __forceinline__ Row8 read_win(const float* p, int t)
{
    const int c = t << 2;
    const float2 L  = *(const float2*)(p + (t == 0 ? 0 : c - 2));
    const float4 M  = *(const float4*)(p + c);
    const float2 Rr = *(const float2*)(p + (t == 255 ? 1022 : c + 4));
    Row8 r;
    r.a[0] = L.x;
    r.a[1] = (t == 0) ? L.x : L.y;        // col -1 -> x[0]
    r.a[2] = M.x; r.a[3] = M.y; r.a[4] = M.z; r.a[5] = M.w;
    r.a[6] = (t == 255) ? Rr.y : Rr.x;    // col 1024 -> x[1023]
    r.a[7] = Rr.y;                         // col 1025 -> x[1023] (Rr.y = p[1023])
    return r;
}

// ---------------- K1: per-plane max (order-free math -> separable) ----------
__global__ __launch_bounds__(256) void hess_max_kernel(
    const float* __restrict__ x, unsigned int* __restrict__ pmax)
{
    __shared__ float lds[RING * SLOTF];
    const int plane = blockIdx.y;
    const int y0 = blockIdx.x * STRIP;
    const int t = threadIdx.x;
    const int wq = (t >> 6) << 8;          // wave-uniform quarter base
    const float* px = x + (size_t)plane * HW;

    // Prologue: issue idx 0..5 = rows y0-1 .. y0+4 into slots 0..5.
#pragma unroll
    for (int k = 0; k < RING; ++k)
        stage(px, y0 - 1 + k, lds + k * SLOTF, wq, t);
    // need idx0,1; newer = idx2..5 = 4 outstanding allowed
    wait_vm_barrier<4>();
    Row8 A = read_win(lds, t);             // row sy-1
    Row8 B = read_win(lds + SLOTF, t);     // row sy

    float smax = 1e-6f;
    int si = 0, sr = 2;
    for (int i = 0; i < STRIP; ++i) {
        if (i < STRIP - 4) {
            stage(px, y0 + i + 5, lds + si * SLOTF, wq, t);   // idx i+6
            si = si + 1 == RING ? 0 : si + 1;
            // need idx i+2; newer = idx i+3..i+6 = 4  (loads only in K1)
            wait_vm_barrier<4>();
        } else {
            wait_vm_barrier<0>();          // tail: exact drain (cheap, loads done)
        }
        Row8 C = read_win(lds + sr * SLOTF, t);               // row sy+1
        sr = sr + 1 == RING ? 0 : sr + 1;

        float P[6], Q[6], Rv[6];
#pragma unroll
        for (int k = 0; k < 6; ++k) {
            P[k]  = fmaf(2.0f, B.a[k + 1], A.a[k + 1]) + C.a[k + 1];
            Q[k]  = fmaf(-2.0f, B.a[k + 1], A.a[k + 1]) + C.a[k + 1];
            Rv[k] = A.a[k + 1] - C.a[k + 1];
        }
#pragma unroll
        for (int j = 0; j < 4; ++j) {
            float gxx = fmaf(-2.0f, P[j + 1], P[j]) + P[j + 2];
            float gyy = fmaf(2.0f, Q[j + 1], Q[j]) + Q[j + 2];
            float gxy = Rv[j + 2] - Rv[j];
            float det = fmaf(gxx, gyy, -(gxy * gxy));
            smax = fmaxf(smax, fabsf(det));
        }
        A = B; B = C;
    }

#pragma unroll
    for (int off = 32; off > 0; off >>= 1)
        smax = fmaxf(smax, __shfl_down(smax, off));
    if ((t & 63) == 0)
        atomicMax(pmax + plane, __float_as_uint(smax));
}

// ---------------- K2: bit-exact scores + NMS + normalize --------------------
struct S6 { float s[6]; };   // scores at cols c-1 .. c+4

__device__ __forceinline__ S6 score_row_exact(const Row8& A, const Row8& B, const Row8& C)
{
    S6 o;
#pragma unroll
    for (int i = 0; i < 6; ++i)
        o.s[i] = score_ref(A.a[i], A.a[i + 1], A.a[i + 2],
                           B.a[i], B.a[i + 1], B.a[i + 2],
                           C.a[i], C.a[i + 1], C.a[i + 2]);
    return o;
}

__global__ __launch_bounds__(256) void hess_nms_kernel(
    const float* __restrict__ x, const unsigned int* __restrict__ pmax,
    float* __restrict__ out)
{
    __shared__ float lds[RING * SLOTF];
    const int plane = blockIdx.y;
    const int y0 = blockIdx.x * STRIP;
    const int t = threadIdx.x;
    const int wq = (t >> 6) << 8;
    const float* px = x + (size_t)plane * HW;
    float* po = out + (size_t)plane * HW;
    const float inv = 1.0f / __uint_as_float(pmax[plane]);

    // Prologue: issue idx 0..5 = rows y0-2 .. y0+3 into slots 0..5.
#pragma unroll
    for (int k = 0; k < RING; ++k)
        stage(px, y0 - 2 + k, lds + k * SLOTF, wq, t);
    // need idx0..4; newer = idx5 = 1
    wait_vm_barrier<1>();
    Row8 rm2 = read_win(lds, t);
    Row8 r0  = read_win(lds + SLOTF, t);
    Row8 r1  = read_win(lds + 2 * SLOTF, t);   // row sy
    Row8 r2  = read_win(lds + 3 * SLOTF, t);   // row sy+1
    Row8 r3  = read_win(lds + 4 * SLOTF, t);   // row sy+2

    S6 zero;
#pragma unroll
    for (int i = 0; i < 6; ++i) zero.s[i] = 0.0f;

    S6 sp = zero;
    if (y0 > 0) sp = score_row_exact(rm2, r0, r1);
    S6 sc_ = score_row_exact(r0, r1, r2);

    // Values of slots 0,1 consumed above; barrier, then reuse slots 0,1.
    barrier_only();
    stage(px, y0 + 4, lds + 0 * SLOTF, wq, t);   // idx6
    stage(px, y0 + 5, lds + 1 * SLOTF, wq, t);   // idx7

    int si = 2, sr = 5;
    for (int i = 0; i < STRIP; ++i) {
        const int sy = y0 + i;
        if (i < STRIP - 3) {
            stage(px, y0 + i + 6, lds + si * SLOTF, wq, t);   // idx i+8
            si = si + 1 == RING ? 0 : si + 1;
        }
        // need idx i+5. FIFO newer-set (loads + NT stores, pinned by asm
        // clobbers): i=0 ->3, i=1 ->4, i=2 ->5, steady ->6, tail -> drain.
        if (i == 0)               wait_vm_barrier<3>();
        else if (i == 1)          wait_vm_barrier<4>();
        else if (i == 2)          wait_vm_barrier<5>();
        else if (i < STRIP - 3)   wait_vm_barrier<6>();
        else                      wait_vm_barrier<0>();

        Row8 r4 = read_win(lds + sr * SLOTF, t);              // row sy+3
        sr = sr + 1 == RING ? 0 : sr + 1;

        S6 sn = zero;
        if (sy + 1 < H) sn = score_row_exact(r1, r2, r3);

        nfloat4 o;
#pragma unroll
        for (int j = 0; j < 4; ++j) {
            float s = sc_.s[j + 1];
            float m = fmaxf(fmaxf(fmaxf(sp.s[j], sp.s[j + 1]), fmaxf(sp.s[j + 2], sc_.s[j])),
                            fmaxf(fmaxf(sc_.s[j + 1], sc_.s[j + 2]),
                                  fmaxf(fmaxf(sn.s[j], sn.s[j + 1]), sn.s[j + 2])));
            o[j] = (s == m) ? s * inv : 0.0f;
        }
        // NT store: don't let the 192 MiB output stream evict the L3-warm input.
        __builtin_nontemporal_store(o, (nfloat4*)(po + (size_t)sy * W + (t << 2)));

        r1 = r2; r2 = r3; r3 = r4;
        sp = sc_; sc_ = sn;
    }
}

extern "C" void kernel_launch(void* const* d_in, const int* in_sizes, int n_in,
                              void* d_out, int out_size, void* d_ws, size_t ws_size,
                              hipStream_t stream) {
    const float* x = (const float*)d_in[0];
    float* out = (float*)d_out;
    unsigned int* pmax = (unsigned int*)d_ws;
    const int planes = in_sizes[0] / HW;   // 48

    hipMemsetAsync(pmax, 0, planes * sizeof(unsigned int), stream);

    dim3 grid(H / STRIP, planes);
    hess_max_kernel<<<grid, 256, 0, stream>>>(x, pmax);
    hess_nms_kernel<<<grid, 256, 0, stream>>>(x, pmax, out);
}

// Round 5
// 407.044 us; speedup vs baseline: 1.0447x; 1.0114x over previous
//
#include <hip/hip_runtime.h>

#define H 1024
#define W 1024
#define HW (H * W)
#define STRIP 32
#define SLOTF 1024            // floats per LDS row slot (no halo; clamp on read)
#define RING 6                // 6-slot ring -> 24576 B LDS, 6 blocks/CU cap

typedef __attribute__((address_space(3))) float lds_f;
typedef const __attribute__((address_space(1))) float g_f;
typedef float nfloat4 __attribute__((ext_vector_type(4)));   // native vec for NT store

// Direct global->LDS DMA, 16B per lane. Dest = wave-uniform base + lane*16
// (our layout: wave w owns floats [256w, 256w+256) of the slot). Src per-lane.
__device__ __forceinline__ void gload16(const float* g, float* l) {
    __builtin_amdgcn_global_load_lds((g_f*)g, (lds_f*)l, 16, 0, 0);
}

// Counted wait + raw barrier in ONE asm with memory clobber: no memory op
// (ds_read, global store, DMA issue) can be moved across it by the compiler,
// which is what makes the FIFO vmcnt accounting below sound.
template<int N>
__device__ __forceinline__ void wait_vm_barrier() {
    asm volatile("s_waitcnt vmcnt(%0)\n\ts_barrier" :: "i"(N) : "memory");
}
__device__ __forceinline__ void barrier_only() {
    asm volatile("s_barrier" ::: "memory");
}

// Issue one row-DMA into a slot (row clamped for edge replication).
__device__ __forceinline__ void stage(const float* px, int row, float* slotbase, int wq, int t) {
    row = row < 0 ? 0 : (row > H - 1 ? H - 1 : row);
    gload16(px + (size_t)row * W + (t << 2), slotbase + wq);
}

// Bit-exact emulation of the numpy fp32 reference (verified, absmax pass):
// direct 9-tap correlation, row-major tap order, sequential fp32 adds.
// fmaf by +-2/+-4 is bit-identical to mul+add (power-of-2 products exact).
// det = p1 - p2 must NOT be contracted -> contract(off).
__device__ __forceinline__ float score_ref(
    float a00, float a01, float a02,
    float a10, float a11, float a12,
    float a20, float a21, float a22)
{
#pragma clang fp contract(off)
    float gxx = fmaf(-2.0f, a01, a00);
    gxx = gxx + a02;
    gxx = fmaf(2.0f, a10, gxx);
    gxx = fmaf(-4.0f, a11, gxx);
    gxx = fmaf(2.0f, a12, gxx);
    gxx = gxx + a20;
    gxx = fmaf(-2.0f, a21, gxx);
    gxx = gxx + a22;
    float gxy = a02 - a00;
    gxy = gxy + a20;
    gxy = gxy - a22;
    float gyy = fmaf(2.0f, a01, a00);
    gyy = gyy + a02;
    gyy = fmaf(-2.0f, a10, gyy);
    gyy = fmaf(-4.0f, a11, gyy);
    gyy = fmaf(-2.0f, a12, gyy);
    gyy = gyy + a20;
    gyy = fmaf(2.0f, a21, gyy);
    gyy = gyy + a22;

    float p1 = gxx * gyy;
    float p2 = gxy * gxy;
    float det = p1 - p2;
    float s = fabsf(det);
    return s > 1e-6f ? s : 1e-6f;
}

struct Row8 { float a[8]; };   // input cols c-2 .. c+5 (c = 4*t)

// Window from an LDS slot with horizontal edge clamp (only lanes 0 / 255).
// b64 @ c-2 (8B aligned), b128 @ c (16B aligned), b64 @ c+4 (8B aligned).
__device__ __forceinline__ Row8 read_win(const float* p, int t)
{
    const int c = t << 2;
    const float2 L  = *(const float2*)(p + (t == 0 ? 0 : c - 2));
    const float4 M  = *(const float4*)(p + c);
    const float2 Rr = *(const float2*)(p + (t == 255 ? 1022 : c + 4));
    Row8 r;
    r.a[0] = L.x;
    r.a[1] = (t == 0) ? L.x : L.y;        // col -1 -> x[0]
    r.a[2] = M.x; r.a[3] = M.y; r.a[4] = M.z; r.a[5] = M.w;
    r.a[6] = (t == 255) ? Rr.y : Rr.x;    // col 1024 -> x[1023]
    r.a[7] = Rr.y;                         // col 1025 -> x[1023] (Rr.y = p[1023])
    return r;
}

// ---------------- K1: per-plane max (order-free math -> separable) ----------
__global__ __launch_bounds__(256) void hess_max_kernel(
    const float* __restrict__ x, unsigned int* __restrict__ pmax)
{
    __shared__ float lds[RING * SLOTF];
    const int plane = blockIdx.y;
    const int y0 = blockIdx.x * STRIP;
    const int t = threadIdx.x;
    const int wq = (t >> 6) << 8;          // wave-uniform quarter base
    const float* px = x + (size_t)plane * HW;

    // Prologue: issue idx 0..5 = rows y0-1 .. y0+4 into slots 0..5.
#pragma unroll
    for (int k = 0; k < RING; ++k)
        stage(px, y0 - 1 + k, lds + k * SLOTF, wq, t);
    // need idx0,1; newer = idx2..5 = 4 outstanding allowed
    wait_vm_barrier<4>();
    Row8 A = read_win(lds, t);             // row sy-1
    Row8 B = read_win(lds + SLOTF, t);     // row sy
    // Race fix: iter0 DMA-overwrites slot0; separate it from the slot0
    // reads above with a barrier (all other slot reuses are 2-barrier
    // separated by construction; only this one wasn't).
    barrier_only();

    float smax = 1e-6f;
    int si = 0, sr = 2;
    for (int i = 0; i < STRIP; ++i) {
        if (i < STRIP - 4) {
            stage(px, y0 + i + 5, lds + si * SLOTF, wq, t);   // idx i+6
            si = si + 1 == RING ? 0 : si + 1;
            // need idx i+2; newer = idx i+3..i+6 = 4  (loads only in K1)
            wait_vm_barrier<4>();
        } else {
            wait_vm_barrier<0>();          // tail: exact drain (cheap, loads done)
        }
        Row8 C = read_win(lds + sr * SLOTF, t);               // row sy+1
        sr = sr + 1 == RING ? 0 : sr + 1;

        float P[6], Q[6], Rv[6];
#pragma unroll
        for (int k = 0; k < 6; ++k) {
            P[k]  = fmaf(2.0f, B.a[k + 1], A.a[k + 1]) + C.a[k + 1];
            Q[k]  = fmaf(-2.0f, B.a[k + 1], A.a[k + 1]) + C.a[k + 1];
            Rv[k] = A.a[k + 1] - C.a[k + 1];
        }
#pragma unroll
        for (int j = 0; j < 4; ++j) {
            float gxx = fmaf(-2.0f, P[j + 1], P[j]) + P[j + 2];
            float gyy = fmaf(2.0f, Q[j + 1], Q[j]) + Q[j + 2];
            float gxy = Rv[j + 2] - Rv[j];
            float det = fmaf(gxx, gyy, -(gxy * gxy));
            smax = fmaxf(smax, fabsf(det));
        }
        A = B; B = C;
    }

#pragma unroll
    for (int off = 32; off > 0; off >>= 1)
        smax = fmaxf(smax, __shfl_down(smax, off));
    if ((t & 63) == 0)
        atomicMax(pmax + plane, __float_as_uint(smax));
}

// ---------------- K2: bit-exact scores + NMS + normalize --------------------
struct S6 { float s[6]; };   // scores at cols c-1 .. c+4

__device__ __forceinline__ S6 score_row_exact(const Row8& A, const Row8& B, const Row8& C)
{
    S6 o;
#pragma unroll
    for (int i = 0; i < 6; ++i)
        o.s[i] = score_ref(A.a[i], A.a[i + 1], A.a[i + 2],
                           B.a[i], B.a[i + 1], B.a[i + 2],
                           C.a[i], C.a[i + 1], C.a[i + 2]);
    return o;
}

__global__ __launch_bounds__(256) void hess_nms_kernel(
    const float* __restrict__ x, const unsigned int* __restrict__ pmax,
    float* __restrict__ out)
{
    __shared__ float lds[RING * SLOTF];
    const int plane = blockIdx.y;
    const int y0 = blockIdx.x * STRIP;
    const int t = threadIdx.x;
    const int wq = (t >> 6) << 8;
    const float* px = x + (size_t)plane * HW;
    float* po = out + (size_t)plane * HW;
    const float inv = 1.0f / __uint_as_float(pmax[plane]);

    // Prologue: issue idx 0..5 = rows y0-2 .. y0+3 into slots 0..5.
#pragma unroll
    for (int k = 0; k < RING; ++k)
        stage(px, y0 - 2 + k, lds + k * SLOTF, wq, t);
    // need idx0..4; newer = idx5 = 1
    wait_vm_barrier<1>();
    Row8 rm2 = read_win(lds, t);
    Row8 r0  = read_win(lds + SLOTF, t);
    Row8 r1  = read_win(lds + 2 * SLOTF, t);   // row sy
    Row8 r2  = read_win(lds + 3 * SLOTF, t);   // row sy+1
    Row8 r3  = read_win(lds + 4 * SLOTF, t);   // row sy+2

    S6 zero;
#pragma unroll
    for (int i = 0; i < 6; ++i) zero.s[i] = 0.0f;

    S6 sp = zero;
    if (y0 > 0) sp = score_row_exact(rm2, r0, r1);
    S6 sc_ = score_row_exact(r0, r1, r2);

    // Values of slots 0,1 consumed above; barrier, then reuse slots 0,1.
    barrier_only();
    stage(px, y0 + 4, lds + 0 * SLOTF, wq, t);   // idx6
    stage(px, y0 + 5, lds + 1 * SLOTF, wq, t);   // idx7

    int si = 2, sr = 5;
    for (int i = 0; i < STRIP; ++i) {
        const int sy = y0 + i;
        if (i < STRIP - 3) {
            stage(px, y0 + i + 6, lds + si * SLOTF, wq, t);   // idx i+8
            si = si + 1 == RING ? 0 : si + 1;
        }
        // need idx i+5. FIFO newer-set (loads + NT stores, pinned by asm
        // clobbers): i=0 ->3, i=1 ->4, i=2 ->5, steady ->6, tail -> drain.
        if (i == 0)               wait_vm_barrier<3>();
        else if (i == 1)          wait_vm_barrier<4>();
        else if (i == 2)          wait_vm_barrier<5>();
        else if (i < STRIP - 3)   wait_vm_barrier<6>();
        else                      wait_vm_barrier<0>();

        Row8 r4 = read_win(lds + sr * SLOTF, t);              // row sy+3
        sr = sr + 1 == RING ? 0 : sr + 1;

        S6 sn = zero;
        if (sy + 1 < H) sn = score_row_exact(r1, r2, r3);

        // Shared-column NMS max: bit-identical to the 9-way tree (max is
        // exactly associative/commutative); 20 fmax instead of 32, and the
        // 3-input maxes fuse to v_max3_f32.
        float m3[6];
#pragma unroll
        for (int k = 0; k < 6; ++k)
            m3[k] = fmaxf(fmaxf(sp.s[k], sc_.s[k]), sn.s[k]);

        nfloat4 o;
#pragma unroll
        for (int j = 0; j < 4; ++j) {
            float s = sc_.s[j + 1];
            float m = fmaxf(fmaxf(m3[j], m3[j + 1]), m3[j + 2]);
            o[j] = (s == m) ? s * inv : 0.0f;
        }
        // NT store: don't let the 192 MiB output stream evict the L3-warm input.
        __builtin_nontemporal_store(o, (nfloat4*)(po + (size_t)sy * W + (t << 2)));

        r1 = r2; r2 = r3; r3 = r4;
        sp = sc_; sc_ = sn;
    }
}

extern "C" void kernel_launch(void* const* d_in, const int* in_sizes, int n_in,
                              void* d_out, int out_size, void* d_ws, size_t ws_size,
                              hipStream_t stream) {
    const float* x = (const float*)d_in[0];
    float* out = (float*)d_out;
    unsigned int* pmax = (unsigned int*)d_ws;
    const int planes = in_sizes[0] / HW;   // 48

    hipMemsetAsync(pmax, 0, planes * sizeof(unsigned int), stream);

    dim3 grid(H / STRIP, planes);
    hess_max_kernel<<<grid, 256, 0, stream>>>(x, pmax);
    hess_nms_kernel<<<grid, 256, 0, stream>>>(x, pmax, out);
}